// Round 8
// baseline (5203.255 us; speedup 1.0000x reference)
//
#include <hip/hip_runtime.h>
#include <math.h>

#define BATCH 8
#define SEQ   2048
#define IN    8
#define HID   256
#define G4    1024   // 4*HID
#define XPR_R 64     // xp ring depth (steps)

typedef unsigned long long u64;
typedef unsigned int u32;

__device__ __forceinline__ float sigmoidf_(float x) { return 1.0f / (1.0f + __expf(-x)); }
__device__ __forceinline__ float tanhf_(float x) { return 1.0f - 2.0f / (__expf(2.0f * x) + 1.0f); }
// padded LDS index for h: +4 words per 32 -> 8 distinct bank groups, conflict-free
__device__ __forceinline__ int hpad(int k) { return k + 4 * (k >> 5); }

// LDS-only barrier (R5: vmcnt-drain removal neutral but harmless; keep).
__device__ __forceinline__ void light_barrier() {
    __asm__ volatile("s_waitcnt lgkmcnt(0)\n\ts_barrier" ::: "memory");
}

// Sum over the 8 lanes {base..base+7} (lane bits 0..2) via VALU DPP (off the DS pipe).
__device__ __forceinline__ float dpp_add8(float v) {
    int x;
    x = __builtin_amdgcn_update_dpp(0, __float_as_int(v), 0xB1, 0xF, 0xF, false);  // quad_perm xor1
    v += __int_as_float(x);
    x = __builtin_amdgcn_update_dpp(0, __float_as_int(v), 0x4E, 0xF, 0xF, false);  // quad_perm xor2
    v += __int_as_float(x);
    x = __builtin_amdgcn_update_dpp(0, __float_as_int(v), 0x141, 0xF, 0xF, false); // row_half_mirror
    v += __int_as_float(x);
    return v;
}

// ---------------------------------------------------------------------------
// R8: hybrid two-level exchange. With grid=96 and b=bid&7, round-robin
// dispatch puts all 12 blocks of a batch's pipeline on ONE XCD (bid%8=b) —
// they share a physically coherent L2 (~200-300cy) that agent-scope atomics
// are forbidden to use (sc0+sc1 bypass, ~500-900cy L3 — the measured ~3000cy
// observe latency, R5/R7 post-mortems). So:
//   publish = plain volatile store (XCD L2 fast path, visible same-XCD)
//           + relaxed agent atomic store (L3 fallback, visible cross-XCD)
//   poll    = alternate sc0 load (L1-bypass, served by local L2 -> sees
//             same-XCD plain publishes) with agent load (L3 truth).
// Correctness NEVER depends on placement: tags are monotone (no ABA), both
// stores carry the same word, and if blocks land cross-XCD the sc0 path may
// stay stale but the agent load guarantees progress. Intra-kernel dirty-L2
// lines are flushed by the kernel-end release, so later kernels reading
// overlaid ws regions are safe.
// ---------------------------------------------------------------------------
__device__ __forceinline__ float poll_tag(const u64* p, u32 tag) {
    u64 v;
    while (true) {
        u64 a;
        __asm__ volatile("global_load_dwordx2 %0, %1, off sc0\n\ts_waitcnt vmcnt(0)"
                         : "=&v"(a) : "v"(p) : "memory");
        if ((u32)(a >> 32) == tag) { v = a; break; }
        a = __hip_atomic_load(p, __ATOMIC_RELAXED, __HIP_MEMORY_SCOPE_AGENT);
        if ((u32)(a >> 32) == tag) { v = a; break; }
    }
    return __uint_as_float((u32)v);
}
__device__ __forceinline__ void pub_tag(u64* p, u32 tag, float x) {
    const u64 pk = ((u64)tag << 32) | (u64)__float_as_uint(x);
    *(volatile u64*)p = pk;   // plain store -> shared XCD L2 (fast path)
    __hip_atomic_store(p, pk, __ATOMIC_RELAXED, __HIP_MEMORY_SCOPE_AGENT);  // L3 fallback
}

__device__ __forceinline__ void matvec8(const float4 (&w4)[4][8], const float* hrow, int ks,
                                        float& a0, float& a1, float& a2, float& a3) {
    a0 = a1 = a2 = a3 = 0.0f;
#pragma unroll
    for (int i = 0; i < 8; i++) {
        const float4 h4 = *(const float4*)(&hrow[36 * ks + 4 * i]);  // 8-lane broadcast
        a0 += w4[0][i].x*h4.x + w4[0][i].y*h4.y + w4[0][i].z*h4.z + w4[0][i].w*h4.w;
        a1 += w4[1][i].x*h4.x + w4[1][i].y*h4.y + w4[1][i].z*h4.z + w4[1][i].w*h4.w;
        a2 += w4[2][i].x*h4.x + w4[2][i].y*h4.y + w4[2][i].z*h4.z + w4[2][i].w*h4.w;
        a3 += w4[3][i].x*h4.x + w4[3][i].y*h4.y + w4[3][i].z*h4.z + w4[3][i].w*h4.w;
    }
}

// ---------------------------------------------------------------------------
// Fused pipelined 2-layer LSTM (R5 structure). Grid = 96 x 512:
//   bid&7 = batch b (same-XCD pipeline under round-robin), role = bid>>3:
//   0-3 L0 q; 4-7 P p; 8-11 L1 q.
// L0 -> h0 tagged write-once stream; P -> xp ring (64 steps, back-pressure
// from L1's parity ring); L1 -> parity ring + plain hbuf.
// Thread (rg=t>>3, ks=t&7) holds 4 rows x 32-col weight slice in 128 VGPRs
// (>= ~256 floats/thread spills — R1/R6 lesson).
// ---------------------------------------------------------------------------
__global__ __launch_bounds__(512, 2) void lstm_fused(
    const float* __restrict__ x,
    const float* __restrict__ w_ih0, const float* __restrict__ w_hh0,
    const float* __restrict__ b_ih0, const float* __restrict__ b_hh0,
    const float* __restrict__ w_ih1, const float* __restrict__ w_hh1,
    const float* __restrict__ b_ih1, const float* __restrict__ b_hh1,
    u64* __restrict__ h0s,    // [8][2048][256] tagged write-once
    u64* __restrict__ xpr,    // [8][64][1024]  tagged ring
    u64* __restrict__ h1r,    // [2][8][256]    tagged parity ring
    float* __restrict__ hbuf) // [8][2048][256] plain h1
{
    const int bid = blockIdx.x;
    const int b    = bid & 7;
    const int role = bid >> 3;
    const int grp  = role >> 2;   // 0 L0, 1 P, 2 L1
    const int q    = role & 3;
    const int t    = threadIdx.x;
    const int ks   = t & 7;
    const int rg   = t >> 3;
    const int wv   = t >> 6;
    const int lane = t & 63;
    const bool isg = (ks == 0);

    __shared__ float h_lds[2][288];
    __shared__ float xbuf[2][256];   // L1: xp values, [gate j][unit] (conflict-free)

    u64* h0b = h0s + (size_t)b * SEQ * HID;
    u64* xpb = xpr + (size_t)b * XPR_R * G4;

    for (int i = t; i < 576; i += 512) ((float*)h_lds)[i] = 0.0f;
    __syncthreads();

    if (grp == 0) {
        // ================= L0: layer-0 recurrence, input proj fused =========
        float4 w4[4][8];
#pragma unroll
        for (int j = 0; j < 4; j++) {
            const float4* wr = (const float4*)(w_hh0 + (size_t)(256*j + 64*q + rg) * HID + ks * 32);
#pragma unroll
            for (int i = 0; i < 8; i++) w4[j][i] = wr[i];
        }
        float4 wi[4][2]; float bs4[4];
#pragma unroll
        for (int j = 0; j < 4; j++) {
            const int G = 256*j + 64*q + rg;
            wi[j][0] = *(const float4*)(w_ih0 + (size_t)G * IN);
            wi[j][1] = *(const float4*)(w_ih0 + (size_t)G * IN + 4);
            bs4[j] = b_ih0[G] + b_hh0[G];
        }
        const float* xb = x + (size_t)b * SEQ * IN;
        float c = 0.0f;
        float xv0 = 0, xv1 = 0, xv2 = 0, xv3 = 0;
        if (isg) {
            const float4 xa = *(const float4*)(xb);
            const float4 xc = *(const float4*)(xb + 4);
            xv0 = bs4[0] + wi[0][0].x*xa.x + wi[0][0].y*xa.y + wi[0][0].z*xa.z + wi[0][0].w*xa.w
                         + wi[0][1].x*xc.x + wi[0][1].y*xc.y + wi[0][1].z*xc.z + wi[0][1].w*xc.w;
            xv1 = bs4[1] + wi[1][0].x*xa.x + wi[1][0].y*xa.y + wi[1][0].z*xa.z + wi[1][0].w*xa.w
                         + wi[1][1].x*xc.x + wi[1][1].y*xc.y + wi[1][1].z*xc.z + wi[1][1].w*xc.w;
            xv2 = bs4[2] + wi[2][0].x*xa.x + wi[2][0].y*xa.y + wi[2][0].z*xa.z + wi[2][0].w*xa.w
                         + wi[2][1].x*xc.x + wi[2][1].y*xc.y + wi[2][1].z*xc.z + wi[2][1].w*xc.w;
            xv3 = bs4[3] + wi[3][0].x*xa.x + wi[3][0].y*xa.y + wi[3][0].z*xa.z + wi[3][0].w*xa.w
                         + wi[3][1].x*xc.x + wi[3][1].y*xc.y + wi[3][1].z*xc.z + wi[3][1].w*xc.w;
        }

        for (int s = 0; s < SEQ; s++) {
            const int cur = s & 1, nxt = cur ^ 1;
            float xn0 = 0, xn1 = 0, xn2 = 0, xn3 = 0;
            if (isg && s + 1 < SEQ) {
                const float4 xa = *(const float4*)(xb + (size_t)(s + 1) * IN);
                const float4 xc = *(const float4*)(xb + (size_t)(s + 1) * IN + 4);
                xn0 = bs4[0] + wi[0][0].x*xa.x + wi[0][0].y*xa.y + wi[0][0].z*xa.z + wi[0][0].w*xa.w
                             + wi[0][1].x*xc.x + wi[0][1].y*xc.y + wi[0][1].z*xc.z + wi[0][1].w*xc.w;
                xn1 = bs4[1] + wi[1][0].x*xa.x + wi[1][0].y*xa.y + wi[1][0].z*xa.z + wi[1][0].w*xa.w
                             + wi[1][1].x*xc.x + wi[1][1].y*xc.y + wi[1][1].z*xc.z + wi[1][1].w*xc.w;
                xn2 = bs4[2] + wi[2][0].x*xa.x + wi[2][0].y*xa.y + wi[2][0].z*xa.z + wi[2][0].w*xa.w
                             + wi[2][1].x*xc.x + wi[2][1].y*xc.y + wi[2][1].z*xc.z + wi[2][1].w*xc.w;
                xn3 = bs4[3] + wi[3][0].x*xa.x + wi[3][0].y*xa.y + wi[3][0].z*xa.z + wi[3][0].w*xa.w
                             + wi[3][1].x*xc.x + wi[3][1].y*xc.y + wi[3][1].z*xc.z + wi[3][1].w*xc.w;
            }
            float a0, a1, a2, a3;
            matvec8(w4, h_lds[cur], ks, a0, a1, a2, a3);
            a0 = dpp_add8(a0); a1 = dpp_add8(a1); a2 = dpp_add8(a2); a3 = dpp_add8(a3);
            const u32 tag = (u32)(s + 1);
            if (isg) {
                const float iv = sigmoidf_(a0 + xv0);
                const float fv = sigmoidf_(a1 + xv1);
                const float gv = tanhf_(a2 + xv2);
                const float ov = sigmoidf_(a3 + xv3);
                c = fv * c + iv * gv;
                const float hv = ov * tanhf_(c);
                const int u = 64*q + rg;
                pub_tag(&h0b[(size_t)s * HID + u], tag, hv);   // publish first (visibility path)
                h_lds[nxt][hpad(u)] = hv;
                xv0 = xn0; xv1 = xn1; xv2 = xn2; xv3 = xn3;
            }
            if (wv >= 1 && wv <= 3) {
                const int u = 64 * ((q + wv) & 3) + lane;
                h_lds[nxt][hpad(u)] = poll_tag(&h0b[(size_t)s * HID + u], tag);
            }
            light_barrier();
        }
    } else if (grp == 1) {
        // ================= P: xp[s] = w_ih1 @ h0[s] + biases ================
        const int p = q;
        float4 w4[4][8]; float bs4[4];
#pragma unroll
        for (int j = 0; j < 4; j++) {
            const int R = 256*p + 64*j + rg;
            const float4* wr = (const float4*)(w_ih1 + (size_t)R * HID + ks * 32);
#pragma unroll
            for (int i = 0; i < 8; i++) w4[j][i] = wr[i];
            bs4[j] = b_ih1[R] + b_hh1[R];
        }
        if (wv >= 4) {   // pre-poll h0[0]
            const int u = 64 * (wv - 4) + lane;
            h_lds[0][hpad(u)] = poll_tag(&h0b[u], 1u);
        }
        __syncthreads();

        for (int s = 0; s < SEQ; s++) {
            const int cur = s & 1, nxt = cur ^ 1;
            float a0, a1, a2, a3;
            matvec8(w4, h_lds[cur], ks, a0, a1, a2, a3);
            a0 = dpp_add8(a0); a1 = dpp_add8(a1); a2 = dpp_add8(a2); a3 = dpp_add8(a3);
            const u32 tag = (u32)(s + 1);
            if (isg) {
                // ring back-pressure: slot s%64 reusable once L1 passed s-64
                if (s >= XPR_R) {
                    const u32 need = (u32)(s - (XPR_R - 1));
                    const u64* bp = h1r + ((size_t)(need & 1u) * 8 + b) * HID + (64*p + rg);
                    u32 tt;
                    do { tt = (u32)(__hip_atomic_load(bp, __ATOMIC_RELAXED, __HIP_MEMORY_SCOPE_AGENT) >> 32); }
                    while (!(tt >= need && tt <= 2048u));
                }
                u64* slot = xpb + (size_t)(s & (XPR_R - 1)) * G4 + 256*p + rg;
                pub_tag(slot +   0, tag, a0 + bs4[0]);
                pub_tag(slot +  64, tag, a1 + bs4[1]);
                pub_tag(slot + 128, tag, a2 + bs4[2]);
                pub_tag(slot + 192, tag, a3 + bs4[3]);
            }
            if (wv >= 4 && s + 1 < SEQ) {   // prefetch h0[s+1]
                const int u = 64 * (wv - 4) + lane;
                h_lds[nxt][hpad(u)] = poll_tag(&h0b[(size_t)(s + 1) * HID + u], tag + 1u);
            }
            light_barrier();
        }
    } else {
        // ================= L1: layer-1 recurrence =========================
        float4 w4[4][8];
#pragma unroll
        for (int j = 0; j < 4; j++) {
            const float4* wr = (const float4*)(w_hh1 + (size_t)(256*j + 64*q + rg) * HID + ks * 32);
#pragma unroll
            for (int i = 0; i < 8; i++) w4[j][i] = wr[i];
        }
        float* ho = hbuf + (size_t)b * SEQ * HID;
        if (wv >= 4) {   // pre-poll xp[0]
            const int j = wv - 4;
            xbuf[0][64*j + lane] = poll_tag(&xpb[256*j + 64*q + lane], 1u);
        }
        __syncthreads();

        float c = 0.0f;
        for (int s = 0; s < SEQ; s++) {
            const int cur = s & 1, nxt = cur ^ 1;
            float a0, a1, a2, a3;
            matvec8(w4, h_lds[cur], ks, a0, a1, a2, a3);
            a0 = dpp_add8(a0); a1 = dpp_add8(a1); a2 = dpp_add8(a2); a3 = dpp_add8(a3);
            const u32 tag = (u32)(s + 1);
            if (isg) {
                const float xq0 = xbuf[cur][rg];
                const float xq1 = xbuf[cur][64 + rg];
                const float xq2 = xbuf[cur][128 + rg];
                const float xq3 = xbuf[cur][192 + rg];
                const float iv = sigmoidf_(a0 + xq0);
                const float fv = sigmoidf_(a1 + xq1);
                const float gv = tanhf_(a2 + xq2);
                const float ov = sigmoidf_(a3 + xq3);
                c = fv * c + iv * gv;
                const float hv = ov * tanhf_(c);
                const int u = 64*q + rg;
                pub_tag(&h1r[((size_t)(tag & 1u) * 8 + b) * HID + u], tag, hv);  // publish first
                h_lds[nxt][hpad(u)] = hv;
                ho[(size_t)s * HID + u] = hv;
            }
            if (wv >= 1 && wv <= 3) {   // peer exchange (parity ring, lockstep)
                const int u = 64 * ((q + wv) & 3) + lane;
                h_lds[nxt][hpad(u)] = poll_tag(&h1r[((size_t)(tag & 1u) * 8 + b) * HID + u], tag);
            }
            if (wv >= 4 && s + 1 < SEQ) {   // prefetch xp[s+1]
                const int j = wv - 4;
                xbuf[nxt][64*j + lane] =
                    poll_tag(&xpb[(size_t)((s + 1) & (XPR_R - 1)) * G4 + 256*j + 64*q + lane], tag + 1u);
            }
            light_barrier();
        }
    }
}

// ---------------------------------------------------------------------------
// K and V projections in one launch (blockIdx.z selects). NT GEMM,
// 128x128x16 tiles, 256 threads, 8x8 micro-tile.
// ---------------------------------------------------------------------------
__global__ __launch_bounds__(256) void gemm_kv(
    const float* __restrict__ A,
    const float* __restrict__ Wk, const float* __restrict__ bk,
    const float* __restrict__ Wv, const float* __restrict__ bv,
    float* __restrict__ Ck, float* __restrict__ Cv, int M, int N, int K)
{
    const float* W    = blockIdx.z ? Wv : Wk;
    const float* bias = blockIdx.z ? bv : bk;
    float*       C    = blockIdx.z ? Cv : Ck;

    __shared__ float As[16][132];
    __shared__ float Bs[16][132];
    const int tid = threadIdx.x;
    const int tx = tid & 15;
    const int ty = tid >> 4;
    const int bm = blockIdx.x * 128;
    const int bn = blockIdx.y * 128;
    const int lrow = tid >> 1;
    const int lk = (tid & 1) * 8;

    float acc[8][8] = {};

    for (int k0 = 0; k0 < K; k0 += 16) {
        const float* ap = A + (size_t)(bm + lrow) * K + k0 + lk;
        const float* wp = W + (size_t)(bn + lrow) * K + k0 + lk;
        const float4 a0 = *(const float4*)ap;
        const float4 a1 = *(const float4*)(ap + 4);
        const float4 w0 = *(const float4*)wp;
        const float4 w1 = *(const float4*)(wp + 4);
        __syncthreads();
        As[lk+0][lrow] = a0.x; As[lk+1][lrow] = a0.y; As[lk+2][lrow] = a0.z; As[lk+3][lrow] = a0.w;
        As[lk+4][lrow] = a1.x; As[lk+5][lrow] = a1.y; As[lk+6][lrow] = a1.z; As[lk+7][lrow] = a1.w;
        Bs[lk+0][lrow] = w0.x; Bs[lk+1][lrow] = w0.y; Bs[lk+2][lrow] = w0.z; Bs[lk+3][lrow] = w0.w;
        Bs[lk+4][lrow] = w1.x; Bs[lk+5][lrow] = w1.y; Bs[lk+6][lrow] = w1.z; Bs[lk+7][lrow] = w1.w;
        __syncthreads();
#pragma unroll
        for (int k = 0; k < 16; k++) {
            const float4 av0 = *(const float4*)(&As[k][ty * 4]);
            const float4 av1 = *(const float4*)(&As[k][64 + ty * 4]);
            const float4 bv0 = *(const float4*)(&Bs[k][tx * 4]);
            const float4 bv1 = *(const float4*)(&Bs[k][64 + tx * 4]);
            const float ar[8] = {av0.x, av0.y, av0.z, av0.w, av1.x, av1.y, av1.z, av1.w};
            const float br[8] = {bv0.x, bv0.y, bv0.z, bv0.w, bv1.x, bv1.y, bv1.z, bv1.w};
#pragma unroll
            for (int i = 0; i < 8; i++)
#pragma unroll
                for (int j = 0; j < 8; j++) acc[i][j] += ar[i] * br[j];
        }
    }

    const int c0 = bn + tx * 4, c1 = bn + 64 + tx * 4;
    const float4 bb0 = *(const float4*)(bias + c0);
    const float4 bb1 = *(const float4*)(bias + c1);
#pragma unroll
    for (int ih = 0; ih < 2; ih++)
#pragma unroll
        for (int i = 0; i < 4; i++) {
            const int row = bm + ih * 64 + ty * 4 + i;
            const int ai = ih * 4 + i;
            float4 o0, o1;
            o0.x = acc[ai][0] + bb0.x; o0.y = acc[ai][1] + bb0.y;
            o0.z = acc[ai][2] + bb0.z; o0.w = acc[ai][3] + bb0.w;
            o1.x = acc[ai][4] + bb1.x; o1.y = acc[ai][5] + bb1.y;
            o1.z = acc[ai][6] + bb1.z; o1.w = acc[ai][7] + bb1.w;
            *(float4*)(C + (size_t)row * N + c0) = o0;
            *(float4*)(C + (size_t)row * N + c1) = o1;
        }
}

// ---------------------------------------------------------------------------
// Q projection at the last position only.
// ---------------------------------------------------------------------------
__global__ __launch_bounds__(256) void qlast_kernel(
    const float* __restrict__ h1, const float* __restrict__ wq,
    const float* __restrict__ bq, float* __restrict__ qout)
{
    const int b = blockIdx.x;
    const int t = threadIdx.x;
    __shared__ __align__(16) float hs[HID];
    hs[t] = h1[((size_t)b * SEQ + (SEQ - 1)) * HID + t];
    __syncthreads();
    const float4* wr = (const float4*)(wq + (size_t)t * HID);
    float acc = 0.0f;
#pragma unroll
    for (int k = 0; k < 64; k++) {
        const float4 wv = wr[k];
        const float4 hv = ((const float4*)hs)[k];
        acc += wv.x*hv.x + wv.y*hv.y + wv.z*hv.z + wv.w*hv.w;
    }
    qout[b * HID + t] = acc + bq[t];
}

// ---------------------------------------------------------------------------
// Decode attention at query S-1 with multiplicative decay on scores.
// ---------------------------------------------------------------------------
__global__ __launch_bounds__(256) void attn_kernel(
    const float* __restrict__ Kb, const float* __restrict__ Vb,
    const float* __restrict__ q, float* __restrict__ attn)
{
    const int b = blockIdx.x >> 2;
    const int h = blockIdx.x & 3;
    const int tid = threadIdx.x;

    __shared__ __align__(16) float qs[64];
    __shared__ float sc[SEQ];
    __shared__ float red[256];
    __shared__ float part[4][64];

    if (tid < 64) qs[tid] = q[b * HID + h * 64 + tid];
    __syncthreads();

    const float LN095 = -0.051293294387550533f;  // ln(0.95)
    for (int k = tid; k < SEQ; k += 256) {
        const float4* kr = (const float4*)(Kb + ((size_t)b * SEQ + k) * HID + h * 64);
        float acc = 0.0f;
#pragma unroll
        for (int d = 0; d < 16; d++) {
            const float4 kv = kr[d];
            const float4 qv = ((const float4*)qs)[d];
            acc += kv.x*qv.x + kv.y*qv.y + kv.z*qv.z + kv.w*qv.w;
        }
        const float dec = __expf(LN095 * (float)(SEQ - 1 - k));
        sc[k] = acc * 0.125f * dec;
    }
    __syncthreads();

    float m = -INFINITY;
    for (int k = tid; k < SEQ; k += 256) m = fmaxf(m, sc[k]);
    red[tid] = m;
    for (int off = 128; off > 0; off >>= 1) {
        __syncthreads();
        if (tid < off) red[tid] = fmaxf(red[tid], red[tid + off]);
    }
    __syncthreads();
    const float mx = red[0];

    float local = 0.0f;
    for (int k = tid; k < SEQ; k += 256) {
        const float p = expf(sc[k] - mx);
        sc[k] = p;
        local += p;
    }
    __syncthreads();
    red[tid] = local;
    for (int off = 128; off > 0; off >>= 1) {
        __syncthreads();
        if (tid < off) red[tid] += red[tid + off];
    }
    __syncthreads();
    const float total = red[0];

    const int chunk = tid >> 6;
    const int d = tid & 63;
    float acc = 0.0f;
    const int k0 = chunk * (SEQ / 4), k1 = (chunk + 1) * (SEQ / 4);
    for (int k = k0; k < k1; k++)
        acc += sc[k] * Vb[((size_t)b * SEQ + k) * HID + h * 64 + d];
    part[chunk][d] = acc;
    __syncthreads();
    if (tid < 64) {
        const float r = (part[0][tid] + part[1][tid]) + (part[2][tid] + part[3][tid]);
        attn[b * HID + h * 64 + tid] = r / total;
    }
}

// ---------------------------------------------------------------------------
// Head: context = attn @ wo^T + bo ; mean/log_var heads (5 each).
// ---------------------------------------------------------------------------
__global__ __launch_bounds__(256) void head_kernel(
    const float* __restrict__ attn, const float* __restrict__ wo,
    const float* __restrict__ bo, const float* __restrict__ w_mean,
    const float* __restrict__ b_mean, const float* __restrict__ w_var,
    const float* __restrict__ b_var, float* __restrict__ out)
{
    const int b = blockIdx.x;
    const int t = threadIdx.x;
    __shared__ __align__(16) float av[HID];
    __shared__ __align__(16) float ctx[HID];
    av[t] = attn[b * HID + t];
    __syncthreads();
    {
        const float4* wr = (const float4*)(wo + (size_t)t * HID);
        float acc = 0.0f;
#pragma unroll
        for (int k = 0; k < 64; k++) {
            const float4 wv = wr[k];
            const float4 hv = ((const float4*)av)[k];
            acc += wv.x*hv.x + wv.y*hv.y + wv.z*hv.z + wv.w*hv.w;
        }
        ctx[t] = acc + bo[t];
    }
    __syncthreads();
    if (t < 5) {
        const float4* wr = (const float4*)(w_mean + (size_t)t * HID);
        float acc = 0.0f;
#pragma unroll
        for (int k = 0; k < 64; k++) {
            const float4 wv = wr[k];
            const float4 hv = ((const float4*)ctx)[k];
            acc += wv.x*hv.x + wv.y*hv.y + wv.z*hv.z + wv.w*hv.w;
        }
        out[b * 5 + t] = acc + b_mean[t];
    } else if (t >= 8 && t < 13) {
        const int m = t - 8;
        const float4* wr = (const float4*)(w_var + (size_t)m * HID);
        float acc = 0.0f;
#pragma unroll
        for (int k = 0; k < 64; k++) {
            const float4 wv = wr[k];
            const float4 hv = ((const float4*)ctx)[k];
            acc += wv.x*hv.x + wv.y*hv.y + wv.z*hv.z + wv.w*hv.w;
        }
        out[BATCH * 5 + b * 5 + m] = acc + b_var[m];
    }
}

// ---------------------------------------------------------------------------
extern "C" void kernel_launch(void* const* d_in, const int* in_sizes, int n_in,
                              void* d_out, int out_size, void* d_ws, size_t ws_size,
                              hipStream_t stream) {
    const float* x      = (const float*)d_in[0];
    const float* w_ih0  = (const float*)d_in[1];
    const float* w_hh0  = (const float*)d_in[2];
    const float* b_ih0  = (const float*)d_in[3];
    const float* b_hh0  = (const float*)d_in[4];
    const float* w_ih1  = (const float*)d_in[5];
    const float* w_hh1  = (const float*)d_in[6];
    const float* b_ih1  = (const float*)d_in[7];
    const float* b_hh1  = (const float*)d_in[8];
    const float* wq     = (const float*)d_in[9];
    const float* bq     = (const float*)d_in[10];
    const float* wk     = (const float*)d_in[11];
    const float* bk     = (const float*)d_in[12];
    const float* wvv    = (const float*)d_in[13];
    const float* bv     = (const float*)d_in[14];
    const float* wo     = (const float*)d_in[15];
    const float* bo     = (const float*)d_in[16];
    const float* w_mean = (const float*)d_in[17];
    const float* b_mean = (const float*)d_in[18];
    const float* w_var  = (const float*)d_in[19];
    const float* b_var  = (const float*)d_in[20];
    float* out = (float*)d_out;

    // ws layout (bytes), ~54 MB peak:
    //  [0, 32M)        h0s tagged stream (fused) -> Kbuf|Vbuf after
    //                  (safe overlay: kernel-end release flushes dirty L2)
    //  [32M, 36M)      xpr ring (fused)          -> qbuf|abuf after
    //  [36M, 36M+32K)  h1r parity ring (fused)
    //  [36M+32K, +16M) hbuf: plain h1 (fused writes; KV/qlast read)
    char* wsb = (char*)d_ws;
    u64*  h0s  = (u64*)(wsb);
    u64*  xpr  = (u64*)(wsb + 33554432);
    u64*  h1r  = (u64*)(wsb + 37748736);
    float* hbuf = (float*)(wsb + 37781504);
    float* Kbuf = (float*)(wsb);
    float* Vbuf = (float*)(wsb + 16777216);
    float* qbuf = (float*)(wsb + 33554432);
    float* abuf = (float*)(wsb + 33554432 + 8192);

    // 1. fused pipelined 2-layer LSTM (h1 -> hbuf)
    lstm_fused<<<96, 512, 0, stream>>>(x, w_ih0, w_hh0, b_ih0, b_hh0,
                                       w_ih1, w_hh1, b_ih1, b_hh1,
                                       h0s, xpr, h1r, hbuf);
    // 2. K and V projections (one launch)
    gemm_kv<<<dim3(128, 2, 2), 256, 0, stream>>>(hbuf, wk, bk, wvv, bv, Kbuf, Vbuf, 16384, 256, 256);
    // 3. Q at last position
    qlast_kernel<<<BATCH, 256, 0, stream>>>(hbuf, wq, bq, qbuf);
    // 4. decode attention with decay
    attn_kernel<<<BATCH * 4, 256, 0, stream>>>(Kbuf, Vbuf, qbuf, abuf);
    // 5. output proj + gaussian head
    head_kernel<<<BATCH, 256, 0, stream>>>(abuf, wo, bo, w_mean, b_mean, w_var, b_var, out);
}

// Round 9
// 3591.260 us; speedup vs baseline: 1.4489x; 1.4489x over previous
//
#include <hip/hip_runtime.h>
#include <math.h>

#define BATCH 8
#define SEQ   2048
#define IN    8
#define HID   256
#define G4    1024   // 4*HID
#define XPR_R 64     // xp ring depth (steps)

typedef unsigned long long u64;
typedef unsigned int u32;

__device__ __forceinline__ float sigmoidf_(float x) { return 1.0f / (1.0f + __expf(-x)); }
__device__ __forceinline__ float tanhf_(float x) { return 1.0f - 2.0f / (__expf(2.0f * x) + 1.0f); }
// padded LDS index for h: +4 words per 32 -> 8 distinct bank groups, conflict-free
__device__ __forceinline__ int hpad(int k) { return k + 4 * (k >> 5); }

// LDS-only barrier (R5: vmcnt-drain removal neutral but harmless; keep).
__device__ __forceinline__ void light_barrier() {
    __asm__ volatile("s_waitcnt lgkmcnt(0)\n\ts_barrier" ::: "memory");
}

// Sum over the 8 lanes {base..base+7} (lane bits 0..2) via VALU DPP (off the DS pipe).
__device__ __forceinline__ float dpp_add8(float v) {
    int x;
    x = __builtin_amdgcn_update_dpp(0, __float_as_int(v), 0xB1, 0xF, 0xF, false);  // quad_perm xor1
    v += __int_as_float(x);
    x = __builtin_amdgcn_update_dpp(0, __float_as_int(v), 0x4E, 0xF, 0xF, false);  // quad_perm xor2
    v += __int_as_float(x);
    x = __builtin_amdgcn_update_dpp(0, __float_as_int(v), 0x141, 0xF, 0xF, false); // row_half_mirror
    v += __int_as_float(x);
    return v;
}

// Tagged u64 word {tag<<32 | f32 bits}: payload inside the atomic word ->
// RELAXED store/load at agent scope (R3 win; R7 swap neutral; R8 hybrid
// regressed — reverted to the R5 form).
__device__ __forceinline__ float poll_tag(const u64* p, u32 tag) {
    u64 v;
    do { v = __hip_atomic_load(p, __ATOMIC_RELAXED, __HIP_MEMORY_SCOPE_AGENT); }
    while ((u32)(v >> 32) != tag);
    return __uint_as_float((u32)v);
}
__device__ __forceinline__ void pub_tag(u64* p, u32 tag, float x) {
    __hip_atomic_store(p, ((u64)tag << 32) | (u64)__float_as_uint(x),
                       __ATOMIC_RELAXED, __HIP_MEMORY_SCOPE_AGENT);
}

// R9: pin a loaded value into a VGPR. Every L-variant since R2 reports
// VGPR_Count=104 < the 128 weight floats/thread -> the compiler has been
// sinking the weight loads INTO the step loop: 256 KB/block/step re-streamed
// from L2 (~3 MB/step/XCD ~ 1700 cy) — a hidden first-order floor that
// explains why all exchange-path tweaks were neutral. A volatile empty asm
// with "+v" can't be duplicated/rematerialized, so the 128 values must stay
// live in registers across the loop (128 + ~80 working < 256 cap at (512,2)).
__device__ __forceinline__ void pin_f4(float4& v) {
    __asm__ volatile("" : "+v"(v.x), "+v"(v.y), "+v"(v.z), "+v"(v.w));
}

__device__ __forceinline__ void matvec8(const float4 (&w4)[4][8], const float* hrow, int ks,
                                        float& a0, float& a1, float& a2, float& a3) {
    a0 = a1 = a2 = a3 = 0.0f;
#pragma unroll
    for (int i = 0; i < 8; i++) {
        const float4 h4 = *(const float4*)(&hrow[36 * ks + 4 * i]);  // 8-lane broadcast
        a0 += w4[0][i].x*h4.x + w4[0][i].y*h4.y + w4[0][i].z*h4.z + w4[0][i].w*h4.w;
        a1 += w4[1][i].x*h4.x + w4[1][i].y*h4.y + w4[1][i].z*h4.z + w4[1][i].w*h4.w;
        a2 += w4[2][i].x*h4.x + w4[2][i].y*h4.y + w4[2][i].z*h4.z + w4[2][i].w*h4.w;
        a3 += w4[3][i].x*h4.x + w4[3][i].y*h4.y + w4[3][i].z*h4.z + w4[3][i].w*h4.w;
    }
}

// ---------------------------------------------------------------------------
// Fused pipelined 2-layer LSTM (R5 structure, 3603us baseline). Grid = 96 x 512:
//   bid&7 = batch b, role = bid>>3: 0-3 L0 q; 4-7 P p; 8-11 L1 q.
// L0 -> h0 tagged write-once stream; P -> xp ring (64 steps, back-pressure
// from L1's parity ring); L1 -> parity ring + plain hbuf.
// Thread (rg=t>>3, ks=t&7) holds 4 rows x 32-col weight slice in 128 VGPRs
// (pinned — see pin_f4).
// ---------------------------------------------------------------------------
__global__ __launch_bounds__(512, 2) void lstm_fused(
    const float* __restrict__ x,
    const float* __restrict__ w_ih0, const float* __restrict__ w_hh0,
    const float* __restrict__ b_ih0, const float* __restrict__ b_hh0,
    const float* __restrict__ w_ih1, const float* __restrict__ w_hh1,
    const float* __restrict__ b_ih1, const float* __restrict__ b_hh1,
    u64* __restrict__ h0s,    // [8][2048][256] tagged write-once
    u64* __restrict__ xpr,    // [8][64][1024]  tagged ring
    u64* __restrict__ h1r,    // [2][8][256]    tagged parity ring
    float* __restrict__ hbuf) // [8][2048][256] plain h1
{
    const int bid = blockIdx.x;
    const int b    = bid & 7;
    const int role = bid >> 3;
    const int grp  = role >> 2;   // 0 L0, 1 P, 2 L1
    const int q    = role & 3;
    const int t    = threadIdx.x;
    const int ks   = t & 7;
    const int rg   = t >> 3;
    const int wv   = t >> 6;
    const int lane = t & 63;
    const bool isg = (ks == 0);

    __shared__ float h_lds[2][288];
    __shared__ float xbuf[2][256];   // L1: xp values, [gate j][unit] (conflict-free)

    u64* h0b = h0s + (size_t)b * SEQ * HID;
    u64* xpb = xpr + (size_t)b * XPR_R * G4;

    for (int i = t; i < 576; i += 512) ((float*)h_lds)[i] = 0.0f;
    __syncthreads();

    if (grp == 0) {
        // ================= L0: layer-0 recurrence, input proj fused =========
        float4 w4[4][8];
#pragma unroll
        for (int j = 0; j < 4; j++) {
            const float4* wr = (const float4*)(w_hh0 + (size_t)(256*j + 64*q + rg) * HID + ks * 32);
#pragma unroll
            for (int i = 0; i < 8; i++) { w4[j][i] = wr[i]; pin_f4(w4[j][i]); }
        }
        float4 wi[4][2]; float bs4[4];
#pragma unroll
        for (int j = 0; j < 4; j++) {
            const int G = 256*j + 64*q + rg;
            wi[j][0] = *(const float4*)(w_ih0 + (size_t)G * IN);
            wi[j][1] = *(const float4*)(w_ih0 + (size_t)G * IN + 4);
            bs4[j] = b_ih0[G] + b_hh0[G];
        }
        const float* xb = x + (size_t)b * SEQ * IN;
        float c = 0.0f;
        float xv0 = 0, xv1 = 0, xv2 = 0, xv3 = 0;
        if (isg) {
            const float4 xa = *(const float4*)(xb);
            const float4 xc = *(const float4*)(xb + 4);
            xv0 = bs4[0] + wi[0][0].x*xa.x + wi[0][0].y*xa.y + wi[0][0].z*xa.z + wi[0][0].w*xa.w
                         + wi[0][1].x*xc.x + wi[0][1].y*xc.y + wi[0][1].z*xc.z + wi[0][1].w*xc.w;
            xv1 = bs4[1] + wi[1][0].x*xa.x + wi[1][0].y*xa.y + wi[1][0].z*xa.z + wi[1][0].w*xa.w
                         + wi[1][1].x*xc.x + wi[1][1].y*xc.y + wi[1][1].z*xc.z + wi[1][1].w*xc.w;
            xv2 = bs4[2] + wi[2][0].x*xa.x + wi[2][0].y*xa.y + wi[2][0].z*xa.z + wi[2][0].w*xa.w
                         + wi[2][1].x*xc.x + wi[2][1].y*xc.y + wi[2][1].z*xc.z + wi[2][1].w*xc.w;
            xv3 = bs4[3] + wi[3][0].x*xa.x + wi[3][0].y*xa.y + wi[3][0].z*xa.z + wi[3][0].w*xa.w
                         + wi[3][1].x*xc.x + wi[3][1].y*xc.y + wi[3][1].z*xc.z + wi[3][1].w*xc.w;
        }

        for (int s = 0; s < SEQ; s++) {
            const int cur = s & 1, nxt = cur ^ 1;
            float xn0 = 0, xn1 = 0, xn2 = 0, xn3 = 0;
            if (isg && s + 1 < SEQ) {
                const float4 xa = *(const float4*)(xb + (size_t)(s + 1) * IN);
                const float4 xc = *(const float4*)(xb + (size_t)(s + 1) * IN + 4);
                xn0 = bs4[0] + wi[0][0].x*xa.x + wi[0][0].y*xa.y + wi[0][0].z*xa.z + wi[0][0].w*xa.w
                             + wi[0][1].x*xc.x + wi[0][1].y*xc.y + wi[0][1].z*xc.z + wi[0][1].w*xc.w;
                xn1 = bs4[1] + wi[1][0].x*xa.x + wi[1][0].y*xa.y + wi[1][0].z*xa.z + wi[1][0].w*xa.w
                             + wi[1][1].x*xc.x + wi[1][1].y*xc.y + wi[1][1].z*xc.z + wi[1][1].w*xc.w;
                xn2 = bs4[2] + wi[2][0].x*xa.x + wi[2][0].y*xa.y + wi[2][0].z*xa.z + wi[2][0].w*xa.w
                             + wi[2][1].x*xc.x + wi[2][1].y*xc.y + wi[2][1].z*xc.z + wi[2][1].w*xc.w;
                xn3 = bs4[3] + wi[3][0].x*xa.x + wi[3][0].y*xa.y + wi[3][0].z*xa.z + wi[3][0].w*xa.w
                             + wi[3][1].x*xc.x + wi[3][1].y*xc.y + wi[3][1].z*xc.z + wi[3][1].w*xc.w;
            }
            float a0, a1, a2, a3;
            matvec8(w4, h_lds[cur], ks, a0, a1, a2, a3);
            a0 = dpp_add8(a0); a1 = dpp_add8(a1); a2 = dpp_add8(a2); a3 = dpp_add8(a3);
            const u32 tag = (u32)(s + 1);
            if (isg) {
                const float iv = sigmoidf_(a0 + xv0);
                const float fv = sigmoidf_(a1 + xv1);
                const float gv = tanhf_(a2 + xv2);
                const float ov = sigmoidf_(a3 + xv3);
                c = fv * c + iv * gv;
                const float hv = ov * tanhf_(c);
                const int u = 64*q + rg;
                pub_tag(&h0b[(size_t)s * HID + u], tag, hv);   // publish first (visibility path)
                h_lds[nxt][hpad(u)] = hv;
                xv0 = xn0; xv1 = xn1; xv2 = xn2; xv3 = xn3;
            }
            if (wv >= 1 && wv <= 3) {
                const int u = 64 * ((q + wv) & 3) + lane;
                h_lds[nxt][hpad(u)] = poll_tag(&h0b[(size_t)s * HID + u], tag);
            }
            light_barrier();
        }
    } else if (grp == 1) {
        // ================= P: xp[s] = w_ih1 @ h0[s] + biases ================
        const int p = q;
        float4 w4[4][8]; float bs4[4];
#pragma unroll
        for (int j = 0; j < 4; j++) {
            const int R = 256*p + 64*j + rg;
            const float4* wr = (const float4*)(w_ih1 + (size_t)R * HID + ks * 32);
#pragma unroll
            for (int i = 0; i < 8; i++) { w4[j][i] = wr[i]; pin_f4(w4[j][i]); }
            bs4[j] = b_ih1[R] + b_hh1[R];
        }
        if (wv >= 4) {   // pre-poll h0[0]
            const int u = 64 * (wv - 4) + lane;
            h_lds[0][hpad(u)] = poll_tag(&h0b[u], 1u);
        }
        __syncthreads();

        for (int s = 0; s < SEQ; s++) {
            const int cur = s & 1, nxt = cur ^ 1;
            float a0, a1, a2, a3;
            matvec8(w4, h_lds[cur], ks, a0, a1, a2, a3);
            a0 = dpp_add8(a0); a1 = dpp_add8(a1); a2 = dpp_add8(a2); a3 = dpp_add8(a3);
            const u32 tag = (u32)(s + 1);
            if (isg) {
                // ring back-pressure: slot s%64 reusable once L1 passed s-64
                if (s >= XPR_R) {
                    const u32 need = (u32)(s - (XPR_R - 1));
                    const u64* bp = h1r + ((size_t)(need & 1u) * 8 + b) * HID + (64*p + rg);
                    u32 tt;
                    do { tt = (u32)(__hip_atomic_load(bp, __ATOMIC_RELAXED, __HIP_MEMORY_SCOPE_AGENT) >> 32); }
                    while (!(tt >= need && tt <= 2048u));
                }
                u64* slot = xpb + (size_t)(s & (XPR_R - 1)) * G4 + 256*p + rg;
                pub_tag(slot +   0, tag, a0 + bs4[0]);
                pub_tag(slot +  64, tag, a1 + bs4[1]);
                pub_tag(slot + 128, tag, a2 + bs4[2]);
                pub_tag(slot + 192, tag, a3 + bs4[3]);
            }
            if (wv >= 4 && s + 1 < SEQ) {   // prefetch h0[s+1]
                const int u = 64 * (wv - 4) + lane;
                h_lds[nxt][hpad(u)] = poll_tag(&h0b[(size_t)(s + 1) * HID + u], tag + 1u);
            }
            light_barrier();
        }
    } else {
        // ================= L1: layer-1 recurrence =========================
        float4 w4[4][8];
#pragma unroll
        for (int j = 0; j < 4; j++) {
            const float4* wr = (const float4*)(w_hh1 + (size_t)(256*j + 64*q + rg) * HID + ks * 32);
#pragma unroll
            for (int i = 0; i < 8; i++) { w4[j][i] = wr[i]; pin_f4(w4[j][i]); }
        }
        float* ho = hbuf + (size_t)b * SEQ * HID;
        if (wv >= 4) {   // pre-poll xp[0]
            const int j = wv - 4;
            xbuf[0][64*j + lane] = poll_tag(&xpb[256*j + 64*q + lane], 1u);
        }
        __syncthreads();

        float c = 0.0f;
        for (int s = 0; s < SEQ; s++) {
            const int cur = s & 1, nxt = cur ^ 1;
            float a0, a1, a2, a3;
            matvec8(w4, h_lds[cur], ks, a0, a1, a2, a3);
            a0 = dpp_add8(a0); a1 = dpp_add8(a1); a2 = dpp_add8(a2); a3 = dpp_add8(a3);
            const u32 tag = (u32)(s + 1);
            if (isg) {
                const float xq0 = xbuf[cur][rg];
                const float xq1 = xbuf[cur][64 + rg];
                const float xq2 = xbuf[cur][128 + rg];
                const float xq3 = xbuf[cur][192 + rg];
                const float iv = sigmoidf_(a0 + xq0);
                const float fv = sigmoidf_(a1 + xq1);
                const float gv = tanhf_(a2 + xq2);
                const float ov = sigmoidf_(a3 + xq3);
                c = fv * c + iv * gv;
                const float hv = ov * tanhf_(c);
                const int u = 64*q + rg;
                pub_tag(&h1r[((size_t)(tag & 1u) * 8 + b) * HID + u], tag, hv);  // publish first
                h_lds[nxt][hpad(u)] = hv;
                ho[(size_t)s * HID + u] = hv;
            }
            if (wv >= 1 && wv <= 3) {   // peer exchange (parity ring, lockstep)
                const int u = 64 * ((q + wv) & 3) + lane;
                h_lds[nxt][hpad(u)] = poll_tag(&h1r[((size_t)(tag & 1u) * 8 + b) * HID + u], tag);
            }
            if (wv >= 4 && s + 1 < SEQ) {   // prefetch xp[s+1]
                const int j = wv - 4;
                xbuf[nxt][64*j + lane] =
                    poll_tag(&xpb[(size_t)((s + 1) & (XPR_R - 1)) * G4 + 256*j + 64*q + lane], tag + 1u);
            }
            light_barrier();
        }
    }
}

// ---------------------------------------------------------------------------
// K and V projections in one launch (blockIdx.z selects). NT GEMM,
// 128x128x16 tiles, 256 threads, 8x8 micro-tile.
// ---------------------------------------------------------------------------
__global__ __launch_bounds__(256) void gemm_kv(
    const float* __restrict__ A,
    const float* __restrict__ Wk, const float* __restrict__ bk,
    const float* __restrict__ Wv, const float* __restrict__ bv,
    float* __restrict__ Ck, float* __restrict__ Cv, int M, int N, int K)
{
    const float* W    = blockIdx.z ? Wv : Wk;
    const float* bias = blockIdx.z ? bv : bk;
    float*       C    = blockIdx.z ? Cv : Ck;

    __shared__ float As[16][132];
    __shared__ float Bs[16][132];
    const int tid = threadIdx.x;
    const int tx = tid & 15;
    const int ty = tid >> 4;
    const int bm = blockIdx.x * 128;
    const int bn = blockIdx.y * 128;
    const int lrow = tid >> 1;
    const int lk = (tid & 1) * 8;

    float acc[8][8] = {};

    for (int k0 = 0; k0 < K; k0 += 16) {
        const float* ap = A + (size_t)(bm + lrow) * K + k0 + lk;
        const float* wp = W + (size_t)(bn + lrow) * K + k0 + lk;
        const float4 a0 = *(const float4*)ap;
        const float4 a1 = *(const float4*)(ap + 4);
        const float4 w0 = *(const float4*)wp;
        const float4 w1 = *(const float4*)(wp + 4);
        __syncthreads();
        As[lk+0][lrow] = a0.x; As[lk+1][lrow] = a0.y; As[lk+2][lrow] = a0.z; As[lk+3][lrow] = a0.w;
        As[lk+4][lrow] = a1.x; As[lk+5][lrow] = a1.y; As[lk+6][lrow] = a1.z; As[lk+7][lrow] = a1.w;
        Bs[lk+0][lrow] = w0.x; Bs[lk+1][lrow] = w0.y; Bs[lk+2][lrow] = w0.z; Bs[lk+3][lrow] = w0.w;
        Bs[lk+4][lrow] = w1.x; Bs[lk+5][lrow] = w1.y; Bs[lk+6][lrow] = w1.z; Bs[lk+7][lrow] = w1.w;
        __syncthreads();
#pragma unroll
        for (int k = 0; k < 16; k++) {
            const float4 av0 = *(const float4*)(&As[k][ty * 4]);
            const float4 av1 = *(const float4*)(&As[k][64 + ty * 4]);
            const float4 bv0 = *(const float4*)(&Bs[k][tx * 4]);
            const float4 bv1 = *(const float4*)(&Bs[k][64 + tx * 4]);
            const float ar[8] = {av0.x, av0.y, av0.z, av0.w, av1.x, av1.y, av1.z, av1.w};
            const float br[8] = {bv0.x, bv0.y, bv0.z, bv0.w, bv1.x, bv1.y, bv1.z, bv1.w};
#pragma unroll
            for (int i = 0; i < 8; i++)
#pragma unroll
                for (int j = 0; j < 8; j++) acc[i][j] += ar[i] * br[j];
        }
    }

    const int c0 = bn + tx * 4, c1 = bn + 64 + tx * 4;
    const float4 bb0 = *(const float4*)(bias + c0);
    const float4 bb1 = *(const float4*)(bias + c1);
#pragma unroll
    for (int ih = 0; ih < 2; ih++)
#pragma unroll
        for (int i = 0; i < 4; i++) {
            const int row = bm + ih * 64 + ty * 4 + i;
            const int ai = ih * 4 + i;
            float4 o0, o1;
            o0.x = acc[ai][0] + bb0.x; o0.y = acc[ai][1] + bb0.y;
            o0.z = acc[ai][2] + bb0.z; o0.w = acc[ai][3] + bb0.w;
            o1.x = acc[ai][4] + bb1.x; o1.y = acc[ai][5] + bb1.y;
            o1.z = acc[ai][6] + bb1.z; o1.w = acc[ai][7] + bb1.w;
            *(float4*)(C + (size_t)row * N + c0) = o0;
            *(float4*)(C + (size_t)row * N + c1) = o1;
        }
}

// ---------------------------------------------------------------------------
// Q projection at the last position only.
// ---------------------------------------------------------------------------
__global__ __launch_bounds__(256) void qlast_kernel(
    const float* __restrict__ h1, const float* __restrict__ wq,
    const float* __restrict__ bq, float* __restrict__ qout)
{
    const int b = blockIdx.x;
    const int t = threadIdx.x;
    __shared__ __align__(16) float hs[HID];
    hs[t] = h1[((size_t)b * SEQ + (SEQ - 1)) * HID + t];
    __syncthreads();
    const float4* wr = (const float4*)(wq + (size_t)t * HID);
    float acc = 0.0f;
#pragma unroll
    for (int k = 0; k < 64; k++) {
        const float4 wv = wr[k];
        const float4 hv = ((const float4*)hs)[k];
        acc += wv.x*hv.x + wv.y*hv.y + wv.z*hv.z + wv.w*hv.w;
    }
    qout[b * HID + t] = acc + bq[t];
}

// ---------------------------------------------------------------------------
// Decode attention at query S-1 with multiplicative decay on scores.
// ---------------------------------------------------------------------------
__global__ __launch_bounds__(256) void attn_kernel(
    const float* __restrict__ Kb, const float* __restrict__ Vb,
    const float* __restrict__ q, float* __restrict__ attn)
{
    const int b = blockIdx.x >> 2;
    const int h = blockIdx.x & 3;
    const int tid = threadIdx.x;

    __shared__ __align__(16) float qs[64];
    __shared__ float sc[SEQ];
    __shared__ float red[256];
    __shared__ float part[4][64];

    if (tid < 64) qs[tid] = q[b * HID + h * 64 + tid];
    __syncthreads();

    const float LN095 = -0.051293294387550533f;  // ln(0.95)
    for (int k = tid; k < SEQ; k += 256) {
        const float4* kr = (const float4*)(Kb + ((size_t)b * SEQ + k) * HID + h * 64);
        float acc = 0.0f;
#pragma unroll
        for (int d = 0; d < 16; d++) {
            const float4 kv = kr[d];
            const float4 qv = ((const float4*)qs)[d];
            acc += kv.x*qv.x + kv.y*qv.y + kv.z*qv.z + kv.w*qv.w;
        }
        const float dec = __expf(LN095 * (float)(SEQ - 1 - k));
        sc[k] = acc * 0.125f * dec;
    }
    __syncthreads();

    float m = -INFINITY;
    for (int k = tid; k < SEQ; k += 256) m = fmaxf(m, sc[k]);
    red[tid] = m;
    for (int off = 128; off > 0; off >>= 1) {
        __syncthreads();
        if (tid < off) red[tid] = fmaxf(red[tid], red[tid + off]);
    }
    __syncthreads();
    const float mx = red[0];

    float local = 0.0f;
    for (int k = tid; k < SEQ; k += 256) {
        const float p = expf(sc[k] - mx);
        sc[k] = p;
        local += p;
    }
    __syncthreads();
    red[tid] = local;
    for (int off = 128; off > 0; off >>= 1) {
        __syncthreads();
        if (tid < off) red[tid] += red[tid + off];
    }
    __syncthreads();
    const float total = red[0];

    const int chunk = tid >> 6;
    const int d = tid & 63;
    float acc = 0.0f;
    const int k0 = chunk * (SEQ / 4), k1 = (chunk + 1) * (SEQ / 4);
    for (int k = k0; k < k1; k++)
        acc += sc[k] * Vb[((size_t)b * SEQ + k) * HID + h * 64 + d];
    part[chunk][d] = acc;
    __syncthreads();
    if (tid < 64) {
        const float r = (part[0][tid] + part[1][tid]) + (part[2][tid] + part[3][tid]);
        attn[b * HID + h * 64 + tid] = r / total;
    }
}

// ---------------------------------------------------------------------------
// Head: context = attn @ wo^T + bo ; mean/log_var heads (5 each).
// ---------------------------------------------------------------------------
__global__ __launch_bounds__(256) void head_kernel(
    const float* __restrict__ attn, const float* __restrict__ wo,
    const float* __restrict__ bo, const float* __restrict__ w_mean,
    const float* __restrict__ b_mean, const float* __restrict__ w_var,
    const float* __restrict__ b_var, float* __restrict__ out)
{
    const int b = blockIdx.x;
    const int t = threadIdx.x;
    __shared__ __align__(16) float av[HID];
    __shared__ __align__(16) float ctx[HID];
    av[t] = attn[b * HID + t];
    __syncthreads();
    {
        const float4* wr = (const float4*)(wo + (size_t)t * HID);
        float acc = 0.0f;
#pragma unroll
        for (int k = 0; k < 64; k++) {
            const float4 wv = wr[k];
            const float4 hv = ((const float4*)av)[k];
            acc += wv.x*hv.x + wv.y*hv.y + wv.z*hv.z + wv.w*hv.w;
        }
        ctx[t] = acc + bo[t];
    }
    __syncthreads();
    if (t < 5) {
        const float4* wr = (const float4*)(w_mean + (size_t)t * HID);
        float acc = 0.0f;
#pragma unroll
        for (int k = 0; k < 64; k++) {
            const float4 wv = wr[k];
            const float4 hv = ((const float4*)ctx)[k];
            acc += wv.x*hv.x + wv.y*hv.y + wv.z*hv.z + wv.w*hv.w;
        }
        out[b * 5 + t] = acc + b_mean[t];
    } else if (t >= 8 && t < 13) {
        const int m = t - 8;
        const float4* wr = (const float4*)(w_var + (size_t)m * HID);
        float acc = 0.0f;
#pragma unroll
        for (int k = 0; k < 64; k++) {
            const float4 wv = wr[k];
            const float4 hv = ((const float4*)ctx)[k];
            acc += wv.x*hv.x + wv.y*hv.y + wv.z*hv.z + wv.w*hv.w;
        }
        out[BATCH * 5 + b * 5 + m] = acc + b_var[m];
    }
}

// ---------------------------------------------------------------------------
extern "C" void kernel_launch(void* const* d_in, const int* in_sizes, int n_in,
                              void* d_out, int out_size, void* d_ws, size_t ws_size,
                              hipStream_t stream) {
    const float* x      = (const float*)d_in[0];
    const float* w_ih0  = (const float*)d_in[1];
    const float* w_hh0  = (const float*)d_in[2];
    const float* b_ih0  = (const float*)d_in[3];
    const float* b_hh0  = (const float*)d_in[4];
    const float* w_ih1  = (const float*)d_in[5];
    const float* w_hh1  = (const float*)d_in[6];
    const float* b_ih1  = (const float*)d_in[7];
    const float* b_hh1  = (const float*)d_in[8];
    const float* wq     = (const float*)d_in[9];
    const float* bq     = (const float*)d_in[10];
    const float* wk     = (const float*)d_in[11];
    const float* bk     = (const float*)d_in[12];
    const float* wvv    = (const float*)d_in[13];
    const float* bv     = (const float*)d_in[14];
    const float* wo     = (const float*)d_in[15];
    const float* bo     = (const float*)d_in[16];
    const float* w_mean = (const float*)d_in[17];
    const float* b_mean = (const float*)d_in[18];
    const float* w_var  = (const float*)d_in[19];
    const float* b_var  = (const float*)d_in[20];
    float* out = (float*)d_out;

    // ws layout (bytes), ~54 MB peak:
    //  [0, 32M)        h0s tagged stream (fused) -> Kbuf|Vbuf after
    //  [32M, 36M)      xpr ring (fused)          -> qbuf|abuf after
    //  [36M, 36M+32K)  h1r parity ring (fused)
    //  [36M+32K, +16M) hbuf: plain h1 (fused writes; KV/qlast read)
    char* wsb = (char*)d_ws;
    u64*  h0s  = (u64*)(wsb);
    u64*  xpr  = (u64*)(wsb + 33554432);
    u64*  h1r  = (u64*)(wsb + 37748736);
    float* hbuf = (float*)(wsb + 37781504);
    float* Kbuf = (float*)(wsb);
    float* Vbuf = (float*)(wsb + 16777216);
    float* qbuf = (float*)(wsb + 33554432);
    float* abuf = (float*)(wsb + 33554432 + 8192);

    // 1. fused pipelined 2-layer LSTM (h1 -> hbuf)
    lstm_fused<<<96, 512, 0, stream>>>(x, w_ih0, w_hh0, b_ih0, b_hh0,
                                       w_ih1, w_hh1, b_ih1, b_hh1,
                                       h0s, xpr, h1r, hbuf);
    // 2. K and V projections (one launch)
    gemm_kv<<<dim3(128, 2, 2), 256, 0, stream>>>(hbuf, wk, bk, wvv, bv, Kbuf, Vbuf, 16384, 256, 256);
    // 3. Q at last position
    qlast_kernel<<<BATCH, 256, 0, stream>>>(hbuf, wq, bq, qbuf);
    // 4. decode attention with decay
    attn_kernel<<<BATCH * 4, 256, 0, stream>>>(Kbuf, Vbuf, qbuf, abuf);
    // 5. output proj + gaussian head
    head_kernel<<<BATCH, 256, 0, stream>>>(abuf, wo, bo, w_mean, b_mean, w_var, b_var, out);
}